// Round 1
// baseline (731.332 us; speedup 1.0000x reference)
//
#include <hip/hip_runtime.h>

#define LEN 128
#define NB 32
#define NC 16
#define NU 16
#define NK 5
#define KC (NK * NC)   // 80 (k,c) pairs
#define LUN (NK * NU)  // 80 (l,u) pairs

// kernel0: transpose coefs[k][l][c][u] -> coefT[kc][lu], kc=k*16+c, lu=l*16+u
__global__ __launch_bounds__(256) void k0_coefT(const float* __restrict__ coefs,
                                                float* __restrict__ coefT) {
    int idx = blockIdx.x * 256 + threadIdx.x;
    if (idx >= KC * LUN) return;
    int kc = idx / LUN, lu = idx % LUN;
    int k = kc >> 4, c = kc & 15;
    int l = lu >> 4, u = lu & 15;
    coefT[idx] = coefs[((k * NK + l) * NC + c) * NU + u];
}

// kernel1: t1[bl][p][k][c][w] = sum_h cheb1[k][h][p] * x[b][c][h][w]
// one block per (b,c); 256 threads; LDS = X tile (64KB) + cheb1 p-slab (16KB)
__global__ __launch_bounds__(256) void k1_cheb_h(const float* __restrict__ x,
                                                 const float* __restrict__ cheb1,
                                                 float* __restrict__ t1, int b0) {
    __shared__ float Xs[LEN * LEN];   // [h][w]
    __shared__ float Cs[LEN * 32];    // [h][p within slab]
    const int c = blockIdx.x;
    const int bl = blockIdx.y;
    const int b = b0 + bl;
    const int tid = threadIdx.x;

    // stage X[b][c] (16384 floats, coalesced float4)
    {
        const float4* xg = (const float4*)(x + (size_t)(b * NC + c) * (LEN * LEN));
        float4* xs4 = (float4*)Xs;
        #pragma unroll
        for (int i = 0; i < 16; ++i) xs4[tid + i * 256] = xg[tid + i * 256];
    }

    const int tx = tid & 31, ty = tid >> 5;
    const int w0 = tx * 4;

    for (int k = 0; k < NK; ++k) {
        for (int slab = 0; slab < 4; ++slab) {
            __syncthreads();  // X staged (first iter) / Cs readers done (later iters)
            // stage Cs[h][pi] = cheb1[k][h][slab*32+pi]
            {
                const float* cg = cheb1 + (size_t)k * LEN * LEN + slab * 32;
                float4* cs4 = (float4*)Cs;
                #pragma unroll
                for (int i = 0; i < 4; ++i) {
                    int fi = tid + i * 256;     // float4 index 0..1023
                    int h = fi >> 3, p4 = fi & 7;
                    cs4[fi] = *(const float4*)(cg + (size_t)h * LEN + p4 * 4);
                }
            }
            __syncthreads();

            float acc[4][4];
            #pragma unroll
            for (int i = 0; i < 4; ++i)
                #pragma unroll
                for (int j = 0; j < 4; ++j) acc[i][j] = 0.f;

            #pragma unroll 4
            for (int h = 0; h < LEN; ++h) {
                float4 xv = *(const float4*)(Xs + h * LEN + w0);
                float4 cv = *(const float4*)(Cs + h * 32 + ty * 4);
                float xa[4] = {xv.x, xv.y, xv.z, xv.w};
                float ca[4] = {cv.x, cv.y, cv.z, cv.w};
                #pragma unroll
                for (int pi = 0; pi < 4; ++pi)
                    #pragma unroll
                    for (int wi = 0; wi < 4; ++wi)
                        acc[pi][wi] += ca[pi] * xa[wi];
            }

            #pragma unroll
            for (int pi = 0; pi < 4; ++pi) {
                int p = slab * 32 + ty * 4 + pi;
                float4 v = make_float4(acc[pi][0], acc[pi][1], acc[pi][2], acc[pi][3]);
                *(float4*)(t1 + ((((size_t)bl * LEN + p) * NK + k) * NC + c) * LEN + w0) = v;
            }
        }
    }
}

// kernel2: per (b,p) block:
//   phase2: s[l][w][u] = sum_{kc} coefT[kc][lu] * t1[bl][p][kc][w]
//   phase3: out[b][u][p][q] = sum_{l,w} s[l][w][u] * cheb2[l][w][q]
__global__ __launch_bounds__(256) void k2_mix_w(const float* __restrict__ t1,
                                                const float* __restrict__ coefT,
                                                const float* __restrict__ cheb2,
                                                float* __restrict__ out, int b0) {
    __shared__ float smA[KC * LEN];        // 40KB: t1 slice [kc][w], later chs [l][wi][q]
    __shared__ float smS[NK * LEN * NU];   // 40KB: s[l][w][u]
    const int p = blockIdx.x;
    const int bl = blockIdx.y;
    const int b = b0 + bl;
    const int tid = threadIdx.x;

    // phase1: stage t1 slice (10240 floats, contiguous, coalesced)
    {
        const float4* src = (const float4*)(t1 + ((size_t)bl * LEN + p) * (KC * LEN));
        float4* dst = (float4*)smA;
        #pragma unroll
        for (int i = 0; i < 10; ++i) dst[tid + i * 256] = src[tid + i * 256];
    }
    __syncthreads();

    // phase2: 80(lu) x 128(w) x 80(kc) GEMM; thread tile = 5 lu x 8 w
    const int tx = tid & 15, ty = tid >> 4;
    const int w0 = tx * 8;
    const int lu0 = ty * 5;
    float acc[5][8];
    #pragma unroll
    for (int j = 0; j < 5; ++j)
        #pragma unroll
        for (int wi = 0; wi < 8; ++wi) acc[j][wi] = 0.f;
    {
        const float* cf = coefT + lu0;
        for (int kc = 0; kc < KC; ++kc) {
            float4 a0 = *(const float4*)(smA + kc * LEN + w0);
            float4 a1 = *(const float4*)(smA + kc * LEN + w0 + 4);
            float tv[8] = {a0.x, a0.y, a0.z, a0.w, a1.x, a1.y, a1.z, a1.w};
            #pragma unroll
            for (int j = 0; j < 5; ++j) {
                float cv = cf[kc * LUN + j];   // global, L1/L2-resident broadcast
                #pragma unroll
                for (int wi = 0; wi < 8; ++wi) acc[j][wi] += cv * tv[wi];
            }
        }
    }
    __syncthreads();  // all smA (t1) reads done before phase3 overwrites it
    #pragma unroll
    for (int j = 0; j < 5; ++j) {
        int lu = lu0 + j, l = lu >> 4, u = lu & 15;
        #pragma unroll
        for (int wi = 0; wi < 8; ++wi)
            smS[(l * LEN + w0 + wi) * NU + u] = acc[j][wi];
    }

    // phase3: thread = (q, 8 u's); w processed in tiles of 16 staged into smA
    const int q = tid & 127, ug = tid >> 7;
    const int u0 = ug * 8;
    float acc2[8];
    #pragma unroll
    for (int i = 0; i < 8; ++i) acc2[i] = 0.f;

    for (int wt = 0; wt < 8; ++wt) {
        __syncthreads();  // previous chs readers done (wt=0: also fences smS writes)
        {
            float4* dst = (float4*)smA;
            #pragma unroll
            for (int i = 0; i < 10; ++i) {
                int fi = tid + i * 256;     // float4 idx 0..2559
                int row = fi >> 5;          // l*16+wi, rows of 128 floats
                int q4 = fi & 31;
                int l = row >> 4, wi = row & 15;
                dst[fi] = *(const float4*)(cheb2 + ((size_t)l * LEN + wt * 16 + wi) * LEN + q4 * 4);
            }
        }
        __syncthreads();

        #pragma unroll
        for (int l = 0; l < NK; ++l) {
            #pragma unroll
            for (int wi = 0; wi < 16; ++wi) {
                int w = wt * 16 + wi;
                float4 s0 = *(const float4*)(smS + (l * LEN + w) * NU + u0);      // broadcast
                float4 s1 = *(const float4*)(smS + (l * LEN + w) * NU + u0 + 4);  // broadcast
                float ch = smA[(l * 16 + wi) * LEN + q];                           // coalesced
                acc2[0] += s0.x * ch; acc2[1] += s0.y * ch;
                acc2[2] += s0.z * ch; acc2[3] += s0.w * ch;
                acc2[4] += s1.x * ch; acc2[5] += s1.y * ch;
                acc2[6] += s1.z * ch; acc2[7] += s1.w * ch;
            }
        }
    }

    #pragma unroll
    for (int i = 0; i < 8; ++i)
        out[(((size_t)b * NU + u0 + i) * LEN + p) * LEN + q] = acc2[i];
}

extern "C" void kernel_launch(void* const* d_in, const int* in_sizes, int n_in,
                              void* d_out, int out_size, void* d_ws, size_t ws_size,
                              hipStream_t stream) {
    const float* x     = (const float*)d_in[0];
    const float* coefs = (const float*)d_in[1];
    const float* cheb1 = (const float*)d_in[2];
    const float* cheb2 = (const float*)d_in[3];
    float* out = (float*)d_out;

    const size_t per_b_bytes = (size_t)NK * NC * LEN * LEN * sizeof(float);  // 5.25 MB
    const size_t coefT_bytes = (size_t)KC * LUN * sizeof(float);             // 25.6 KB

    float* t1 = (float*)d_ws;
    size_t avail = (ws_size > coefT_bytes + 256) ? (ws_size - coefT_bytes - 256) : 0;
    int chunk = (int)(avail / per_b_bytes);
    if (chunk < 1) chunk = 1;
    if (chunk > NB) chunk = NB;
    float* coefT = (float*)((char*)d_ws + ((ws_size - coefT_bytes) & ~(size_t)15));

    hipLaunchKernelGGL(k0_coefT, dim3(25), dim3(256), 0, stream, coefs, coefT);
    for (int b0 = 0; b0 < NB; b0 += chunk) {
        int cb = (NB - b0 < chunk) ? (NB - b0) : chunk;
        hipLaunchKernelGGL(k1_cheb_h, dim3(NC, cb), dim3(256), 0, stream, x, cheb1, t1, b0);
        hipLaunchKernelGGL(k2_mix_w, dim3(LEN, cb), dim3(256), 0, stream, t1, coefT, cheb2, out, b0);
    }
}

// Round 2
// 207.062 us; speedup vs baseline: 3.5319x; 3.5319x over previous
//
#include <hip/hip_runtime.h>

#define LEN 128
#define NB 32
#define NC 16
#define NU 16
#define NK 5
#define KC 80          // (k,c) pairs
#define KCP 96         // padded K for stage2
#define LUN 80         // (l,u) pairs

typedef unsigned int uint32;
typedef unsigned short ushort16;
typedef __attribute__((ext_vector_type(8))) short bf16x8;
typedef __attribute__((ext_vector_type(4))) float f32x4;

#define MFMA(a, b, c) __builtin_amdgcn_mfma_f32_16x16x32_bf16(a, b, c, 0, 0, 0)

static __device__ inline ushort16 f2bf(float f) {
    union { float f; uint32 u; } v; v.f = f;
    uint32 u = v.u;
    uint32 r = (u + 0x7fffu + ((u >> 16) & 1u)) >> 16;   // RNE
    return (ushort16)r;
}
static __device__ inline uint32 pack2(float a, float b) {
    return (uint32)f2bf(a) | ((uint32)f2bf(b) << 16);
}
static __device__ inline bf16x8 frag4(const uint32* p) {
    union { uint32 u[4]; bf16x8 v; } t;
    t.u[0] = p[0]; t.u[1] = p[1]; t.u[2] = p[2]; t.u[3] = p[3];
    return t.v;
}
static __device__ inline bf16x8 frag16(const void* p) {   // 16B-aligned
    return *(const bf16x8*)p;
}

// ---------------- k0: precompute bf16 operand layouts ----------------
// cheb1T[kp=k*128+p][h]  (640x128)   = cheb1[k][h][p]
// cheb2T[q][l*128+w]     (128x640)   = cheb2[l][w][q]
// coefTT[lu=l*16+u][kc]  (80x96, kc>=80 zero) = coefs[k][l][c][u]
__global__ __launch_bounds__(256) void k0_prep(const float* __restrict__ coefs,
                                               const float* __restrict__ cheb1,
                                               const float* __restrict__ cheb2,
                                               ushort16* __restrict__ cheb1T,
                                               ushort16* __restrict__ cheb2T,
                                               ushort16* __restrict__ coefTT) {
    int i = blockIdx.x * 256 + threadIdx.x;
    if (i < 81920) {
        int kp = i >> 7, h = i & 127;
        int k = kp >> 7, p = kp & 127;
        cheb1T[i] = f2bf(cheb1[(k * LEN + h) * LEN + p]);
    } else if (i < 163840) {
        int j = i - 81920;
        int q = j / 640, t = j % 640;
        int l = t >> 7, w = t & 127;
        cheb2T[j] = f2bf(cheb2[(l * LEN + w) * LEN + q]);
    } else if (i < 171520) {
        int j = i - 163840;
        int lu = j / KCP, kc = j % KCP;
        int l = lu >> 4, u = lu & 15, k = kc >> 4, c = kc & 15;
        coefTT[j] = (kc < KC) ? f2bf(coefs[((k * NK + l) * NC + c) * NU + u]) : (ushort16)0;
    }
}

// ---------------- k1: t1[bl][p][k][c][w] = sum_h cheb1[k][h][p]*x[b][c][h][w]
// per (c, bl) block: GEMM M=640 (kp, 10 tiles of 64), N=128 (w), K=128 (h)
__global__ __launch_bounds__(256) void k1_mfma(const float* __restrict__ x,
                                               const uint32* __restrict__ cheb1T,  // dword view: row=64 dw
                                               ushort16* __restrict__ t1, int b0) {
    __shared__ __align__(16) uint32 Xs[128 * 65];  // [w][h-pairs], stride 65 dw
    __shared__ __align__(16) uint32 As[64 * 65];   // [r][h-pairs]
    const int c = blockIdx.x, bl = blockIdx.y, b = b0 + bl;
    const int tid = threadIdx.x;

    // stage Xs (transpose + cvt): conflict-free (stride 65: bank = w + h2 mod 32)
    {
        const float* xp = x + (size_t)(b * NC + c) * (LEN * LEN);
        int w = tid & 127, hp0 = tid >> 7;
        for (int h2 = hp0; h2 < 64; h2 += 2) {
            float f0 = xp[(2 * h2) * LEN + w];
            float f1 = xp[(2 * h2 + 1) * LEN + w];
            Xs[w * 65 + h2] = pack2(f0, f1);
        }
    }

    const int lane = tid & 63, wave = tid >> 6;
    const int m16 = lane & 15, g = lane >> 4;
    const int msub = (wave & 1) * 32;      // wave covers 32 rows
    const int n0 = (wave >> 1) * 64;       // and 64 w-cols

    for (int tile = 0; tile < 10; ++tile) {
        __syncthreads();   // prev-iter As readers done (iter0: no-op)
        #pragma unroll
        for (int i = 0; i < 16; ++i) {
            int fi = tid + i * 256;
            int r = fi >> 6, d = fi & 63;
            As[r * 65 + d] = cheb1T[(size_t)(tile * 64 + r) * 64 + d];
        }
        __syncthreads();   // As ready (and, iter0, Xs ready)

        bf16x8 Af[2][4];
        #pragma unroll
        for (int mi = 0; mi < 2; ++mi)
            #pragma unroll
            for (int ks = 0; ks < 4; ++ks)
                Af[mi][ks] = frag4(As + (msub + mi * 16 + m16) * 65 + ks * 16 + g * 4);

        f32x4 acc[2][4];
        #pragma unroll
        for (int mi = 0; mi < 2; ++mi)
            #pragma unroll
            for (int ni = 0; ni < 4; ++ni)
                acc[mi][ni] = (f32x4)0.f;

        #pragma unroll
        for (int ni = 0; ni < 4; ++ni) {
            #pragma unroll
            for (int ks = 0; ks < 4; ++ks) {
                bf16x8 Bf = frag4(Xs + (n0 + ni * 16 + m16) * 65 + ks * 16 + g * 4);
                acc[0][ni] = MFMA(Af[0][ks], Bf, acc[0][ni]);
                acc[1][ni] = MFMA(Af[1][ks], Bf, acc[1][ni]);
            }
        }

        #pragma unroll
        for (int mi = 0; mi < 2; ++mi)
            #pragma unroll
            for (int ni = 0; ni < 4; ++ni)
                #pragma unroll
                for (int r = 0; r < 4; ++r) {
                    int kp = tile * 64 + msub + mi * 16 + g * 4 + r;
                    int k = kp >> 7, p = kp & 127;
                    int w = n0 + ni * 16 + m16;
                    t1[((((size_t)bl * LEN + p) * NK + k) * NC + c) * LEN + w] = f2bf(acc[mi][ni][r]);
                }
    }
}

// ---------------- k2: per (p, bl) block
// stage2: s[lu][w] = sum_kc coefTT[lu][kc] * t1slice[kc][w]   (M=80,N=128,K=96)
// stage3: out[b][u][p][q] = sum_{l,w} s[l*16+u][w] * cheb2T[q][l*128+w]  (M=16,N=128,K=640)
__global__ __launch_bounds__(256) void k2_mfma(const ushort16* __restrict__ t1,
                                               const ushort16* __restrict__ coefTT,
                                               const ushort16* __restrict__ cheb2T,
                                               float* __restrict__ out, int b0) {
    __shared__ __align__(16) uint32 Ts[128 * 49];   // [w][kc-pairs], stride 49 dw
    __shared__ __align__(16) uint32 A3[16 * 324];   // [u][(l,w)-pairs], stride 324 dw (16B aligned)
    const int p = blockIdx.x, bl = blockIdx.y, b = b0 + bl;
    const int tid = threadIdx.x;

    // stage + transpose t1 slice: read row pairs, write (kc,kc+1)-packed dwords
    {
        const uint32* t1u = (const uint32*)(t1 + (size_t)(bl * LEN + p) * (KC * LEN));
        #pragma unroll
        for (int i = 0; i < 10; ++i) {
            int fi = tid + i * 256;          // 0..2559
            int kc2 = fi >> 6, w2 = fi & 63; // kc pair, w pair
            uint32 da = t1u[(2 * kc2) * 64 + w2];
            uint32 db = t1u[(2 * kc2 + 1) * 64 + w2];
            uint32 lo = (da & 0xffffu) | (db << 16);
            uint32 hi = (da >> 16) | (db & 0xffff0000u);
            Ts[(2 * w2) * 49 + kc2] = lo;
            Ts[(2 * w2 + 1) * 49 + kc2] = hi;
        }
        for (int j = tid; j < 128 * 9; j += 256) {    // zero K-pad kc 80..95 (+pad dw)
            int w = j / 9, d = 40 + (j % 9);
            Ts[w * 49 + d] = 0;
        }
    }
    __syncthreads();

    const int lane = tid & 63, wave = tid >> 6;
    const int n16 = lane & 15, g = lane >> 4;
    const int nbase = wave * 32;   // wave covers 32 n-cols

    // stage2
    f32x4 acc[5][2];
    #pragma unroll
    for (int mi = 0; mi < 5; ++mi) { acc[mi][0] = (f32x4)0.f; acc[mi][1] = (f32x4)0.f; }
    #pragma unroll
    for (int ks = 0; ks < 3; ++ks) {
        bf16x8 Bf[2];
        #pragma unroll
        for (int nt = 0; nt < 2; ++nt)
            Bf[nt] = frag4(Ts + (nbase + nt * 16 + n16) * 49 + ks * 16 + g * 4);
        #pragma unroll
        for (int mi = 0; mi < 5; ++mi) {
            bf16x8 Af = frag16(coefTT + (size_t)(mi * 16 + n16) * KCP + ks * 32 + g * 8);
            acc[mi][0] = MFMA(Af, Bf[0], acc[mi][0]);
            acc[mi][1] = MFMA(Af, Bf[1], acc[mi][1]);
        }
    }
    // s -> A3 bf16 (A-operand layout for stage3): row u (stride 648 bf16), col l*128+w
    {
        ushort16* A3s = (ushort16*)A3;
        #pragma unroll
        for (int mi = 0; mi < 5; ++mi)        // mi == l
            #pragma unroll
            for (int nt = 0; nt < 2; ++nt)
                #pragma unroll
                for (int r = 0; r < 4; ++r) {
                    int u = g * 4 + r;
                    int w = nbase + nt * 16 + n16;
                    A3s[u * 648 + mi * 128 + w] = f2bf(acc[mi][nt][r]);
                }
    }
    __syncthreads();

    // stage3
    f32x4 acc3[2] = {(f32x4)0.f, (f32x4)0.f};
    const ushort16* A3r = (const ushort16*)A3;
    #pragma unroll
    for (int ks = 0; ks < 20; ++ks) {
        bf16x8 Af = frag16(A3r + n16 * 648 + ks * 32 + g * 8);       // ds_read_b128
        #pragma unroll
        for (int nt = 0; nt < 2; ++nt) {
            int q = nbase + nt * 16 + n16;
            bf16x8 Bf = frag16(cheb2T + (size_t)q * 640 + ks * 32 + g * 8);  // L2-resident
            acc3[nt] = MFMA(Af, Bf, acc3[nt]);
        }
    }
    #pragma unroll
    for (int nt = 0; nt < 2; ++nt)
        #pragma unroll
        for (int r = 0; r < 4; ++r) {
            int u = g * 4 + r;
            int q = nbase + nt * 16 + n16;
            out[(((size_t)b * NU + u) * LEN + p) * LEN + q] = acc3[nt][r];
        }
}

extern "C" void kernel_launch(void* const* d_in, const int* in_sizes, int n_in,
                              void* d_out, int out_size, void* d_ws, size_t ws_size,
                              hipStream_t stream) {
    const float* x     = (const float*)d_in[0];
    const float* coefs = (const float*)d_in[1];
    const float* cheb1 = (const float*)d_in[2];
    const float* cheb2 = (const float*)d_in[3];
    float* out = (float*)d_out;

    const size_t aux_bytes = 163840 + 163840 + 15360;          // cheb1T + cheb2T + coefTT
    size_t aux_off = (ws_size - aux_bytes) & ~(size_t)255;
    ushort16* cheb1T = (ushort16*)((char*)d_ws + aux_off);
    ushort16* cheb2T = cheb1T + 81920;
    ushort16* coefTT = cheb2T + 81920;
    ushort16* t1 = (ushort16*)d_ws;

    const size_t per_b = (size_t)NK * NC * LEN * LEN * sizeof(ushort16);   // 327680 B
    int chunk = (int)(aux_off / per_b);
    if (chunk < 1) chunk = 1;
    if (chunk > NB) chunk = NB;

    hipLaunchKernelGGL(k0_prep, dim3((171520 + 255) / 256), dim3(256), 0, stream,
                       coefs, cheb1, cheb2, cheb1T, cheb2T, coefTT);
    for (int b0 = 0; b0 < NB; b0 += chunk) {
        int cb = (NB - b0 < chunk) ? (NB - b0) : chunk;
        hipLaunchKernelGGL(k1_mfma, dim3(NC, cb), dim3(256), 0, stream,
                           x, (const uint32*)cheb1T, t1, b0);
        hipLaunchKernelGGL(k2_mfma, dim3(LEN, cb), dim3(256), 0, stream,
                           t1, coefTT, cheb2T, out, b0);
    }
}

// Round 3
// 174.164 us; speedup vs baseline: 4.1991x; 1.1889x over previous
//
#include <hip/hip_runtime.h>
#include <hip/hip_bf16.h>

#define LEN 128
#define NB 32
#define NC 16
#define NU 16
#define NK 5
#define KC 80          // (k,c) pairs
#define KCP 96         // padded K for stage2
#define LUN 80         // (l,u) pairs

typedef unsigned int uint32;
typedef unsigned short ushort16;
typedef __attribute__((ext_vector_type(8))) short bf16x8;
typedef __attribute__((ext_vector_type(4))) float f32x4;

#define MFMA(a, b, c) __builtin_amdgcn_mfma_f32_16x16x32_bf16(a, b, c, 0, 0, 0)

static __device__ inline ushort16 f2bf(float f) {
    union { float f; uint32 u; } v; v.f = f;
    uint32 u = v.u;
    uint32 r = (u + 0x7fffu + ((u >> 16) & 1u)) >> 16;   // RNE
    return (ushort16)r;
}
static __device__ inline uint32 pkbf(float a, float b) {   // low=a, high=b
    return (uint32)f2bf(a) | ((uint32)f2bf(b) << 16);
}
static __device__ inline bf16x8 frag16(const void* p) {    // 16B-aligned
    return *(const bf16x8*)p;
}

// ---------------- k0: precompute bf16 operand layouts ----------------
// cheb1T[kp=k*128+p][h]  (640x128)   = cheb1[k][h][p]
// cheb2T[q][l*128+w]     (128x640)   = cheb2[l][w][q]
// coefTT[lu=l*16+u][kc]  (80x96, kc>=80 zero) = coefs[k][l][c][u]
__global__ __launch_bounds__(256) void k0_prep(const float* __restrict__ coefs,
                                               const float* __restrict__ cheb1,
                                               const float* __restrict__ cheb2,
                                               ushort16* __restrict__ cheb1T,
                                               ushort16* __restrict__ cheb2T,
                                               ushort16* __restrict__ coefTT) {
    int i = blockIdx.x * 256 + threadIdx.x;
    if (i < 81920) {
        int kp = i >> 7, h = i & 127;
        int k = kp >> 7, p = kp & 127;
        cheb1T[i] = f2bf(cheb1[(k * LEN + h) * LEN + p]);
    } else if (i < 163840) {
        int j = i - 81920;
        int q = j / 640, t = j % 640;
        int l = t >> 7, w = t & 127;
        cheb2T[j] = f2bf(cheb2[(l * LEN + w) * LEN + q]);
    } else if (i < 171520) {
        int j = i - 163840;
        int lu = j / KCP, kc = j % KCP;
        int l = lu >> 4, u = lu & 15, k = kc >> 4, c = kc & 15;
        coefTT[j] = (kc < KC) ? f2bf(coefs[((k * NK + l) * NC + c) * NU + u]) : (ushort16)0;
    }
}

// ---------------- k1: t1[bl][p][k][c][w] = sum_h cheb1[k][h][p]*x[b][c][h][w]
// per (c,bl) block. GEMM M=128 (w), N=640 (kp, 4 passes of 160), K=128 (h).
// Wave tile: 64 w (4 m-tiles) x 80 kp (5 n-tiles), waves 2x2.
__global__ __launch_bounds__(256, 2) void k1_mfma(const float* __restrict__ x,
                                                  const uint32* __restrict__ cheb1T,  // dword view, 64 dw/row
                                                  ushort16* __restrict__ t1, int b0) {
    __shared__ __align__(16) uint32 Xs[128 * 68];  // A: [w][h-pairs], stride 68 dw (16B-mult)
    __shared__ __align__(16) uint32 As[160 * 68];  // B: [kp][h-pairs], stride 68 dw
    const int c = blockIdx.x, bl = blockIdx.y, b = b0 + bl;
    const int tid = threadIdx.x;
    const int lane = tid & 63, wave = tid >> 6;
    const int m16 = lane & 15, g = lane >> 4;
    const int wm = wave >> 1, wn = wave & 1;

    // stage Xs (transpose + cvt), coalesced along w
    {
        const float* xp = x + (size_t)(b * NC + c) * (LEN * LEN);
        int w = tid & 127, hg = tid >> 7;
        #pragma unroll 4
        for (int i = 0; i < 32; ++i) {
            int h2 = hg * 32 + i;
            float f0 = xp[(2 * h2) * LEN + w];
            float f1 = xp[(2 * h2 + 1) * LEN + w];
            Xs[w * 68 + h2] = pkbf(f0, f1);
        }
    }

    for (int pass = 0; pass < 4; ++pass) {
        __syncthreads();   // prev As readers done (pass0: also orders Xs writes)
        #pragma unroll
        for (int i = 0; i < 10; ++i) {
            int it = tid + i * 256;          // 0..2559
            int r = it >> 4, cc = it & 15;
            uint4 v = *(const uint4*)(cheb1T + (size_t)(pass * 160 + r) * 64 + cc * 4);
            *(uint4*)(As + r * 68 + cc * 4) = v;
        }
        __syncthreads();

        f32x4 acc[4][5];
        #pragma unroll
        for (int mi = 0; mi < 4; ++mi)
            #pragma unroll
            for (int ni = 0; ni < 5; ++ni) acc[mi][ni] = (f32x4)0.f;

        #pragma unroll
        for (int ks = 0; ks < 4; ++ks) {
            bf16x8 Af[4], Bf[5];
            #pragma unroll
            for (int mi = 0; mi < 4; ++mi)
                Af[mi] = frag16(Xs + (wm * 64 + mi * 16 + m16) * 68 + ks * 16 + g * 4);
            #pragma unroll
            for (int ni = 0; ni < 5; ++ni)
                Bf[ni] = frag16(As + (wn * 80 + ni * 16 + m16) * 68 + ks * 16 + g * 4);
            #pragma unroll
            for (int mi = 0; mi < 4; ++mi)
                #pragma unroll
                for (int ni = 0; ni < 5; ++ni)
                    acc[mi][ni] = MFMA(Af[mi], Bf[ni], acc[mi][ni]);
        }

        // epilogue: lane holds 4 consecutive w at fixed kp -> dwordx2 stores
        #pragma unroll
        for (int ni = 0; ni < 5; ++ni) {
            int kp = pass * 160 + wn * 80 + ni * 16 + m16;
            int k = kp >> 7, p = kp & 127;
            size_t base = (((size_t)(bl * LEN + p) * NK + k) * NC + c) * LEN;
            #pragma unroll
            for (int mi = 0; mi < 4; ++mi) {
                int w0 = wm * 64 + mi * 16 + g * 4;
                uint2 d;
                d.x = pkbf(acc[mi][ni][0], acc[mi][ni][1]);
                d.y = pkbf(acc[mi][ni][2], acc[mi][ni][3]);
                *(uint2*)((ushort16*)t1 + base + w0) = d;
            }
        }
    }
}

// ---------------- k2: per (pg, bl) block, 2 p-slices (p = 2pg, 2pg+1)
// stage2: s[w(256)][lu(80)] = Ts[w][kc] x coefTT[lu][kc], K=96
// stage3: out[pu(32)][q(128)] = A3[pu][lw] x cheb2T[q][lw], K=640
__global__ __launch_bounds__(256, 2) void k2_mfma(const ushort16* __restrict__ t1,
                                                  const ushort16* __restrict__ coefTT,
                                                  const ushort16* __restrict__ cheb2T,
                                                  float* __restrict__ out, int b0) {
    __shared__ __align__(16) uint32 sm[2 * 128 * 52];   // Ts [p][w][kc2], stride 52 dw; A3 aliases
    const int pg = blockIdx.x, bl = blockIdx.y, b = b0 + bl;
    const int tid = threadIdx.x;
    const int lane = tid & 63, wave = tid >> 6;
    const int n16 = lane & 15, g = lane >> 4;

    // stage t1 (2 contiguous 20KB slices) -> Ts[w][kc] (kc-pairs packed in dwords)
    {
        const uint32* t1u = (const uint32*)(t1 + (size_t)(bl * LEN + 2 * pg) * (KC * LEN));
        #pragma unroll
        for (int i = 0; i < 5; ++i) {
            int it = tid + i * 256;          // 0..1279
            int p_i = (it >= 640) ? 1 : 0;
            int rem = it - 640 * p_i;
            int kc2 = rem >> 4, wq = rem & 15;
            const uint32* src = t1u + p_i * 5120 + kc2 * 128 + wq * 4;
            uint4 Av = *(const uint4*)(src);
            uint4 Bv = *(const uint4*)(src + 64);
            uint32* dst = sm + (p_i * 128 + wq * 8) * 52 + kc2;
            const uint32* av = (const uint32*)&Av;
            const uint32* bv = (const uint32*)&Bv;
            #pragma unroll
            for (int j = 0; j < 4; ++j) {
                dst[(2 * j) * 52]     = (av[j] & 0xffffu) | (bv[j] << 16);
                dst[(2 * j + 1) * 52] = (av[j] >> 16) | (bv[j] & 0xffff0000u);
            }
        }
        for (int j = tid; j < 2048; j += 256) {   // zero K-pad (kc2 40..47)
            int row = j >> 3, d = j & 7;
            sm[row * 52 + 40 + d] = 0;
        }
    }
    __syncthreads();

    // ---- stage2: wave = (wp = wave>>1 -> p, ww = wave&1 -> w-half)
    const int wp = wave >> 1, ww = wave & 1;
    f32x4 acc[4][5];
    #pragma unroll
    for (int mi = 0; mi < 4; ++mi)
        #pragma unroll
        for (int ni = 0; ni < 5; ++ni) acc[mi][ni] = (f32x4)0.f;

    #pragma unroll
    for (int ks = 0; ks < 3; ++ks) {
        bf16x8 Af[4], Bf[5];
        #pragma unroll
        for (int mi = 0; mi < 4; ++mi)
            Af[mi] = frag16(sm + (wp * 128 + ww * 64 + mi * 16 + n16) * 52 + ks * 16 + g * 4);
        #pragma unroll
        for (int ni = 0; ni < 5; ++ni)
            Bf[ni] = frag16(coefTT + (size_t)(ni * 16 + n16) * KCP + ks * 32 + g * 8);
        #pragma unroll
        for (int mi = 0; mi < 4; ++mi)
            #pragma unroll
            for (int ni = 0; ni < 5; ++ni)
                acc[mi][ni] = MFMA(Af[mi], Bf[ni], acc[mi][ni]);
    }
    __syncthreads();   // all Ts reads done; A3 may overwrite

    // s -> A3 bf16 A-layout: row pu = p_local*16+u (stride 648 bf16), col l*128+w
    {
        ushort16* A3 = (ushort16*)sm;
        #pragma unroll
        for (int mi = 0; mi < 4; ++mi)
            #pragma unroll
            for (int ni = 0; ni < 5; ++ni) {
                int lu = ni * 16 + n16, u = lu & 15, l = lu >> 4;
                int w0 = ww * 64 + mi * 16 + g * 4;
                int pu = wp * 16 + u;
                uint2 d;
                d.x = pkbf(acc[mi][ni][0], acc[mi][ni][1]);
                d.y = pkbf(acc[mi][ni][2], acc[mi][ni][3]);
                *(uint2*)(A3 + pu * 648 + l * 128 + w0) = d;
            }
    }
    __syncthreads();

    // ---- stage3: M=32 (pu), wave owns 32 q
    const ushort16* A3r = (const ushort16*)sm;
    f32x4 c3[2][2];
    c3[0][0] = (f32x4)0.f; c3[0][1] = (f32x4)0.f;
    c3[1][0] = (f32x4)0.f; c3[1][1] = (f32x4)0.f;
    #pragma unroll 5
    for (int ks = 0; ks < 20; ++ks) {
        bf16x8 Af2[2], Bf2[2];
        #pragma unroll
        for (int mi = 0; mi < 2; ++mi)
            Af2[mi] = frag16(A3r + (mi * 16 + n16) * 648 + ks * 32 + g * 8);
        #pragma unroll
        for (int nt = 0; nt < 2; ++nt)
            Bf2[nt] = frag16(cheb2T + (size_t)(wave * 32 + nt * 16 + n16) * 640 + ks * 32 + g * 8);
        #pragma unroll
        for (int mi = 0; mi < 2; ++mi)
            #pragma unroll
            for (int nt = 0; nt < 2; ++nt)
                c3[mi][nt] = MFMA(Af2[mi], Bf2[nt], c3[mi][nt]);
    }

    #pragma unroll
    for (int mi = 0; mi < 2; ++mi)
        #pragma unroll
        for (int nt = 0; nt < 2; ++nt)
            #pragma unroll
            for (int r = 0; r < 4; ++r) {
                int u = g * 4 + r;
                int q = wave * 32 + nt * 16 + n16;
                out[(((size_t)(b * NU + u)) * LEN + (2 * pg + mi)) * LEN + q] = c3[mi][nt][r];
            }
}

extern "C" void kernel_launch(void* const* d_in, const int* in_sizes, int n_in,
                              void* d_out, int out_size, void* d_ws, size_t ws_size,
                              hipStream_t stream) {
    const float* x     = (const float*)d_in[0];
    const float* coefs = (const float*)d_in[1];
    const float* cheb1 = (const float*)d_in[2];
    const float* cheb2 = (const float*)d_in[3];
    float* out = (float*)d_out;

    const size_t aux_bytes = 163840 + 163840 + 15360;          // cheb1T + cheb2T + coefTT
    size_t aux_off = (ws_size - aux_bytes) & ~(size_t)255;
    ushort16* cheb1T = (ushort16*)((char*)d_ws + aux_off);
    ushort16* cheb2T = cheb1T + 81920;
    ushort16* coefTT = cheb2T + 81920;
    ushort16* t1 = (ushort16*)d_ws;

    const size_t per_b = (size_t)NK * NC * LEN * LEN * sizeof(ushort16);   // 327680 B
    int chunk = (int)(aux_off / per_b);
    if (chunk < 1) chunk = 1;
    if (chunk > NB) chunk = NB;

    hipLaunchKernelGGL(k0_prep, dim3((171520 + 255) / 256), dim3(256), 0, stream,
                       coefs, cheb1, cheb2, cheb1T, cheb2T, coefTT);
    for (int b0 = 0; b0 < NB; b0 += chunk) {
        int cb = (NB - b0 < chunk) ? (NB - b0) : chunk;
        hipLaunchKernelGGL(k1_mfma, dim3(NC, cb), dim3(256), 0, stream,
                           x, (const uint32*)cheb1T, t1, b0);
        hipLaunchKernelGGL(k2_mfma, dim3(64, cb), dim3(256), 0, stream,
                           t1, coefTT, cheb2T, out, b0);
    }
}